// Round 4
// baseline (129418.848 us; speedup 1.0000x reference)
//
#include <hip/hip_runtime.h>
#include <stdint.h>

// ---------------- problem dims ----------------
#define T_FRAMES 8192
#define DIM_D 512
#define DIM_J 640
#define DIM_E 512
#define DIM_H 640
#define DIM_V 4096
#define G4H   2560
#define TOK_BLANK 4095
#define NBLK 256
#define NTHR 256

// ---------------- workspace layout (bytes) ----------------
// h2 / x words: [tag32 | f32 bits]. crit word: [tag16 | max_f32_bits32 | idx16].
#define WS_HW   0                      // u64[640]  raw h2
#define WS_XW   (WS_HW + 640*8)        // u64[640]  x = tanh(enc+dp)
#define WS_SA   (WS_XW + 640*8)        // u64[256]  crit (tag16|max|idx)
#define WS_SB   (WS_SA + 256*8)        // u64[256]  tag32|sum_exp
#define WS_BAR  (WS_SB + 256*8)        // u32[256*16] init barrier flags

__device__ __forceinline__ float sigm(float x) { return 1.f / (1.f + __expf(-x)); }

__device__ __forceinline__ void st64(unsigned long long* p, unsigned tag, unsigned pay) {
  __hip_atomic_store(p, ((unsigned long long)tag << 32) | (unsigned long long)pay,
                     __ATOMIC_RELAXED, __HIP_MEMORY_SCOPE_AGENT);
}
__device__ __forceinline__ unsigned long long ld64(const unsigned long long* p) {
  return __hip_atomic_load(p, __ATOMIC_RELAXED, __HIP_MEMORY_SCOPE_AGENT);
}
// monotone tag check; 0xAAAAAAAA poison -> negative signed diff -> not ready
__device__ __forceinline__ bool tagok(unsigned long long w, unsigned tag) {
  return (int)((unsigned)(w >> 32) - tag) >= 0;
}
__device__ __forceinline__ bool tagok16(unsigned long long w, unsigned tag16) {
  return (short)((unsigned short)(w >> 48) - (unsigned short)tag16) >= 0;
}

// classic release/acquire grid barrier -- used ONCE after init
__device__ __forceinline__ void gbar_init(unsigned* flags, int bid, int tid) {
  __syncthreads();
  if (tid == 0)
    __hip_atomic_store(&flags[bid * 16], 1u, __ATOMIC_RELEASE, __HIP_MEMORY_SCOPE_AGENT);
  unsigned f;
  do { f = __hip_atomic_load(&flags[tid * 16], __ATOMIC_RELAXED, __HIP_MEMORY_SCOPE_AGENT); }
  while ((int)(f - 1u) < 0);
  __builtin_amdgcn_fence(__ATOMIC_ACQUIRE, "agent");
  __syncthreads();
}

extern "C" __global__ void __launch_bounds__(NTHR, 1)
rnnt_greedy3(const float* __restrict__ enc,
             const float* __restrict__ embed,
             const float* __restrict__ Wx,
             const float* __restrict__ Wh,
             const float* __restrict__ b_lstm,
             const float* __restrict__ Wdp,
             const float* __restrict__ bdp,
             const float* __restrict__ Wenc,
             const float* __restrict__ benc,
             const float* __restrict__ Wout,
             const float* __restrict__ bout,
             float* __restrict__ out,
             unsigned long long* __restrict__ hw,
             unsigned long long* __restrict__ xw,
             unsigned long long* __restrict__ sA,
             unsigned long long* __restrict__ sB,
             unsigned* __restrict__ barflag)
{
  __shared__ float smem[28512];     // 114,048 B -> 1 block/CU

  const int tid  = threadIdx.x;
  const int bid  = blockIdx.x;
  const int wid  = tid >> 6;
  const int lane = tid & 63;

  float* woutl = smem;              // 16*640  Wout slice [vl][j]
  float* wxl   = smem + 10240;      // 12*512  Wx cols  [c][k]
  float* whl   = smem + 16384;      // 12*640  Wh cols  [c][k]
  float* wdpl  = smem + 24064;      // 3*640   Wdp cols [jl][k]
  float* h_com = smem + 25984;      // 640 committed h (replicated)
  float* h2_l  = smem + 26624;      // 640 raw h2
  float* x_l   = smem + 27264;      // 640 x = tanh(enc+dp)
  float* ebuf  = smem + 27904;      // 512 embed[tok]
  float* logit_l = smem + 28416;    // 16
  float* g_l     = smem + 28432;    // 12
  float* c_l     = smem + 28444;    // 4  owned c slice
  float* dpc_l   = smem + 28448;    // 4  owned committed dp
  float* bout_l  = smem + 28452;    // 16
  float* blst_l  = smem + 28468;    // 12
  float* bdp_l   = smem + 28480;    // 4
  float* red     = smem + 28484;    // 16 scratch (tok broadcast)
  float* enc_lds = smem;            // init overlay 32*512 = 16384 floats

  const int h0 = (bid * 5) >> 1;    // owned h == owned j slice
  const int h1 = ((bid + 1) * 5) >> 1;
  const int nH = h1 - h0;           // 2 or 3
  const int ncols = nH * 4;
  const int vb = bid << 4;          // 16 vocab entries per block

  // ================= init: enc_proj -> out[t][0:640] =================
  {
    const int r0 = bid * 32;
    const float4* src = (const float4*)(enc + (size_t)r0 * DIM_D);
    float4* dst = (float4*)enc_lds;
    for (int i = tid; i < 32 * DIM_D / 4; i += NTHR) dst[i] = src[i];
    __syncthreads();
    for (int jj = tid; jj < DIM_J; jj += NTHR) {
      float acc[32];
      #pragma unroll
      for (int r = 0; r < 32; ++r) acc[r] = 0.f;
      for (int k = 0; k < DIM_D; ++k) {
        float w = Wenc[(size_t)k * DIM_J + jj];
        #pragma unroll
        for (int r = 0; r < 32; ++r) acc[r] += enc_lds[r * DIM_D + k] * w;
      }
      float bj = benc[jj];
      for (int r = 0; r < 32; ++r) out[(size_t)(r0 + r) * DIM_V + jj] = acc[r] + bj;
    }
    __syncthreads();
  }

  // ================= init: weight slices -> LDS =================
  for (int idx = tid; idx < 16 * DIM_J; idx += NTHR) {
    int vl = idx / DIM_J, j = idx - vl * DIM_J;
    woutl[idx] = Wout[(size_t)j * DIM_V + vb + vl];
  }
  for (int idx = tid; idx < ncols * DIM_E; idx += NTHR) {
    int c = idx >> 9, k = idx & 511;
    int gcol = (c & 3) * DIM_H + h0 + (c >> 2);
    wxl[idx] = Wx[(size_t)k * G4H + gcol];
  }
  for (int idx = tid; idx < ncols * DIM_H; idx += NTHR) {
    int c = idx / DIM_H, k = idx - c * DIM_H;
    int gcol = (c & 3) * DIM_H + h0 + (c >> 2);
    whl[idx] = Wh[(size_t)k * G4H + gcol];
  }
  for (int idx = tid; idx < nH * DIM_H; idx += NTHR) {
    int jl = idx / DIM_H, k = idx - jl * DIM_H;
    wdpl[idx] = Wdp[(size_t)k * DIM_J + h0 + jl];
  }
  if (tid < 16) bout_l[tid] = bout[vb + tid];
  if (tid < ncols) blst_l[tid] = b_lstm[(tid & 3) * DIM_H + h0 + (tid >> 2)];
  if (tid < nH) bdp_l[tid] = bdp[h0 + tid];
  for (int i = tid; i < DIM_H; i += NTHR) h_com[i] = 0.f;
  if (tid < 4) c_l[tid] = 0.f;

  gbar_init(barflag, bid, tid);   // one-time: enc_proj + LDS ready everywhere

  // LSTM column assignment: waves {0,2,3} -> slots {0,1,2}, cols slot+3*i
  const int  slot = (wid == 0) ? 0 : wid - 1;
  const int  c0 = slot, c1 = slot + 3, c2 = slot + 6, c3 = slot + 9;
  const bool v2 = (c2 < ncols), v3 = (c3 < ncols);
  const bool lstmw = (wid != 1);

  // ================= main loop (t = -1 is the BLANK priming step) =================
  for (int t = -1; t < T_FRAMES; ++t) {
    const unsigned TAG = (unsigned)(t + 2);
    const bool last = (t == T_FRAMES - 1);

    // prefetch own enc_proj scalars for row t+1 (consumed at x-build)
    float encj = 0.f;
    {
      int prow = (t + 1 < T_FRAMES) ? (t + 1) : (T_FRAMES - 1);
      if (wid < nH && lane == 0) encj = out[(size_t)prow * DIM_V + h0 + wid];
    }

    int tok; bool nb;
    if (t >= 0) {
      // ---- P1: logits slice from x_l (all 4 waves, 4 vocab entries each) ----
      {
        const float* w0 = woutl + (wid * 4 + 0) * DIM_J;
        const float* w1 = woutl + (wid * 4 + 1) * DIM_J;
        const float* w2 = woutl + (wid * 4 + 2) * DIM_J;
        const float* w3 = woutl + (wid * 4 + 3) * DIM_J;
        float a0 = 0, a1 = 0, a2 = 0, a3 = 0;
        #pragma unroll
        for (int i = 0; i < 10; ++i) {
          int k = lane + (i << 6);
          float xv = x_l[k];
          a0 += xv * w0[k]; a1 += xv * w1[k]; a2 += xv * w2[k]; a3 += xv * w3[k];
        }
        #pragma unroll
        for (int s = 32; s; s >>= 1) {
          a0 += __shfl_xor(a0, s); a1 += __shfl_xor(a1, s);
          a2 += __shfl_xor(a2, s); a3 += __shfl_xor(a3, s);
        }
        if (lane == 0) {
          logit_l[wid * 4 + 0] = a0 + bout_l[wid * 4 + 0];
          logit_l[wid * 4 + 1] = a1 + bout_l[wid * 4 + 1];
          logit_l[wid * 4 + 2] = a2 + bout_l[wid * 4 + 2];
          logit_l[wid * 4 + 3] = a3 + bout_l[wid * 4 + 3];
        }
      }
      __syncthreads();

      // ---- wave0: block stats, publish crit + sumexp, poll crit, argmax ----
      if (wid == 0) {
        float v  = (lane < 16) ? logit_l[lane] : -3.4e38f;
        int   vi = vb + (lane & 15);
        float m = v; int mi = vi;
        #pragma unroll
        for (int s = 32; s; s >>= 1) {
          float om = __shfl_xor(m, s); int oi = __shfl_xor(mi, s);
          if (om > m || (om == m && oi < mi)) { m = om; mi = oi; }
        }
        float e = (lane < 16) ? __expf(v) : 0.f;   // direct exp; |logit| small
        #pragma unroll
        for (int s = 32; s; s >>= 1) e += __shfl_xor(e, s);
        if (lane == 0) {
          unsigned long long cw = ((unsigned long long)(TAG & 0xffffu) << 48)
                                | ((unsigned long long)__float_as_uint(m) << 16)
                                | (unsigned long long)(unsigned)(mi & 0xffff);
          __hip_atomic_store(sA + bid, cw, __ATOMIC_RELAXED, __HIP_MEMORY_SCOPE_AGENT);
          st64(sB + bid, TAG, __float_as_uint(e));
        }
        // poll all 256 crit words (4 per lane, coalesced)
        unsigned long long cv0 = 0, cv1 = 0, cv2 = 0, cv3 = 0;
        unsigned rdy = 0;
        while (rdy != 0xfu) {
          if (!(rdy & 1u)) { unsigned long long w = ld64(sA + lane);        if (tagok16(w, TAG)) { cv0 = w; rdy |= 1u; } }
          if (!(rdy & 2u)) { unsigned long long w = ld64(sA + lane + 64);   if (tagok16(w, TAG)) { cv1 = w; rdy |= 2u; } }
          if (!(rdy & 4u)) { unsigned long long w = ld64(sA + lane + 128);  if (tagok16(w, TAG)) { cv2 = w; rdy |= 4u; } }
          if (!(rdy & 8u)) { unsigned long long w = ld64(sA + lane + 192);  if (tagok16(w, TAG)) { cv3 = w; rdy |= 8u; } }
          if (rdy != 0xfu) __builtin_amdgcn_s_sleep(1);
        }
        float bm = -3.4e38f; int bi = 0x7fffffff;
        {
          float mm; int ii;
          mm = __uint_as_float((unsigned)(cv0 >> 16)); ii = ((int)lane << 4)        | (int)(cv0 & 0xfu) | (int)((cv0 >> 4) & 0xff0u);
          // idx16 holds the FULL vocab index (<=4095); just unpack it:
          ii = (int)(cv0 & 0xffffu);
          if (mm > bm || (mm == bm && ii < bi)) { bm = mm; bi = ii; }
          mm = __uint_as_float((unsigned)(cv1 >> 16)); ii = (int)(cv1 & 0xffffu);
          if (mm > bm || (mm == bm && ii < bi)) { bm = mm; bi = ii; }
          mm = __uint_as_float((unsigned)(cv2 >> 16)); ii = (int)(cv2 & 0xffffu);
          if (mm > bm || (mm == bm && ii < bi)) { bm = mm; bi = ii; }
          mm = __uint_as_float((unsigned)(cv3 >> 16)); ii = (int)(cv3 & 0xffffu);
          if (mm > bm || (mm == bm && ii < bi)) { bm = mm; bi = ii; }
        }
        #pragma unroll
        for (int s = 32; s; s >>= 1) {
          float om = __shfl_xor(bm, s); int oi = __shfl_xor(bi, s);
          if (om > bm || (om == bm && oi < bi)) { bm = om; bi = oi; }
        }
        if (lane == 0) ((int*)red)[0] = bi;
      }
      __syncthreads();   // (A) tok visible
      tok = ((int*)red)[0];
      nb = (tok != TOK_BLANK);
    } else {
      tok = TOK_BLANK; nb = true;
    }

    // ---- phase 2a: ebuf load (w2,3) + wh-dot (w0,2,3) + lse/logp (w1) ----
    float4 ev;
    if (wid >= 2 && !last) ev = *(const float4*)(embed + (size_t)tok * DIM_E + (tid - 128) * 4);
    float acc0 = 0, acc1 = 0, acc2 = 0, acc3 = 0;
    if (lstmw && !last) {
      #pragma unroll
      for (int i = 0; i < 10; ++i) {
        int k = lane + (i << 6);
        float hv = h_com[k];
        acc0 += hv * whl[c0 * DIM_H + k];
        acc1 += hv * whl[c1 * DIM_H + k];
        if (v2) acc2 += hv * whl[c2 * DIM_H + k];
        if (v3) acc3 += hv * whl[c3 * DIM_H + k];
      }
    }
    if (wid == 1 && t >= 0) {
      // poll sum-exp words, compute lse, write this block's 16 logp values
      unsigned long long s0 = 0, s1 = 0, s2 = 0, s3 = 0;
      unsigned rdy = 0;
      while (rdy != 0xfu) {
        if (!(rdy & 1u)) { unsigned long long w = ld64(sB + lane);        if (tagok(w, TAG)) { s0 = w; rdy |= 1u; } }
        if (!(rdy & 2u)) { unsigned long long w = ld64(sB + lane + 64);   if (tagok(w, TAG)) { s1 = w; rdy |= 2u; } }
        if (!(rdy & 4u)) { unsigned long long w = ld64(sB + lane + 128);  if (tagok(w, TAG)) { s2 = w; rdy |= 4u; } }
        if (!(rdy & 8u)) { unsigned long long w = ld64(sB + lane + 192);  if (tagok(w, TAG)) { s3 = w; rdy |= 8u; } }
        if (rdy != 0xfu) __builtin_amdgcn_s_sleep(1);
      }
      float s = __uint_as_float((unsigned)s0) + __uint_as_float((unsigned)s1)
              + __uint_as_float((unsigned)s2) + __uint_as_float((unsigned)s3);
      #pragma unroll
      for (int sh = 32; sh; sh >>= 1) s += __shfl_xor(s, sh);
      float lse = __logf(s);
      if (lane < 16) out[(size_t)t * DIM_V + vb + lane] = logit_l[lane] - lse;
    }
    if (wid >= 2 && !last) *(float4*)(ebuf + (tid - 128) * 4) = ev;
    __syncthreads();   // (B) ebuf visible; logp done
    if (last) break;

    // ---- phase 2b: wx-dot + gate reduce ----
    if (lstmw) {
      #pragma unroll
      for (int i = 0; i < 8; ++i) {
        int k = lane + (i << 6);
        float evv = ebuf[k];
        acc0 += evv * wxl[c0 * DIM_E + k];
        acc1 += evv * wxl[c1 * DIM_E + k];
        if (v2) acc2 += evv * wxl[c2 * DIM_E + k];
        if (v3) acc3 += evv * wxl[c3 * DIM_E + k];
      }
      #pragma unroll
      for (int s = 32; s; s >>= 1) {
        acc0 += __shfl_xor(acc0, s); acc1 += __shfl_xor(acc1, s);
        acc2 += __shfl_xor(acc2, s); acc3 += __shfl_xor(acc3, s);
      }
      if (lane == 0) {
        g_l[c0] = acc0 + blst_l[c0];
        g_l[c1] = acc1 + blst_l[c1];
        if (v2) g_l[c2] = acc2 + blst_l[c2];
        if (v3) g_l[c3] = acc3 + blst_l[c3];
      }
    }
    __syncthreads();   // (C) gates ready

    // ---- gate combine + h2 publish (wave0 lanes 0..nH-1), wave0 polls h2 ----
    if (tid < nH) {
      float c_old = c_l[tid];
      float gi = g_l[tid * 4 + 0], gf = g_l[tid * 4 + 1];
      float gg = g_l[tid * 4 + 2], go_ = g_l[tid * 4 + 3];
      float c2v = sigm(gf) * c_old + sigm(gi) * tanhf(gg);
      float h2v = sigm(go_) * tanhf(c2v);
      c_l[tid] = nb ? c2v : c_old;
      st64(hw + h0 + tid, TAG, __float_as_uint(h2v));
    }
    if (wid == 0) {
      unsigned long long hv[10]; unsigned rdy = 0;
      while (rdy != 0x3ffu) {
        #pragma unroll
        for (int i = 0; i < 10; ++i) {
          if (!(rdy & (1u << i))) {
            unsigned long long w = ld64(hw + lane + (i << 6));
            if (tagok(w, TAG)) { hv[i] = w; rdy |= 1u << i; }
          }
        }
        if (rdy != 0x3ffu) __builtin_amdgcn_s_sleep(1);
      }
      #pragma unroll
      for (int i = 0; i < 10; ++i) {
        int k = lane + (i << 6);
        float h2v = __uint_as_float((unsigned)hv[i]);
        h2_l[k] = h2v;
        h_com[k] = nb ? h2v : h_com[k];
      }
    }
    __syncthreads();   // (D) h2_l ready

    // ---- dp + x publish (waves 0..nH-1), wave0 polls x ----
    if (wid < nH) {
      const float* wp = wdpl + wid * DIM_H;
      float a = 0.f;
      #pragma unroll
      for (int i = 0; i < 10; ++i) { int k = lane + (i << 6); a += h2_l[k] * wp[k]; }
      #pragma unroll
      for (int s = 32; s; s >>= 1) a += __shfl_xor(a, s);
      if (lane == 0) {
        float dp2 = a + bdp_l[wid];
        float dpn = nb ? dp2 : dpc_l[wid];
        dpc_l[wid] = dpn;
        st64(xw + h0 + wid, TAG, __float_as_uint(tanhf(encj + dpn)));
      }
    }
    if (wid == 0) {
      unsigned long long xv[10]; unsigned rdy = 0;
      while (rdy != 0x3ffu) {
        #pragma unroll
        for (int i = 0; i < 10; ++i) {
          if (!(rdy & (1u << i))) {
            unsigned long long w = ld64(xw + lane + (i << 6));
            if (tagok(w, TAG)) { xv[i] = w; rdy |= 1u << i; }
          }
        }
        if (rdy != 0x3ffu) __builtin_amdgcn_s_sleep(1);
      }
      #pragma unroll
      for (int i = 0; i < 10; ++i)
        x_l[lane + (i << 6)] = __uint_as_float((unsigned)xv[i]);
    }
    __syncthreads();   // (E) x ready for next step
  }
}

extern "C" void kernel_launch(void* const* d_in, const int* in_sizes, int n_in,
                              void* d_out, int out_size, void* d_ws, size_t ws_size,
                              hipStream_t stream) {
  const float* enc    = (const float*)d_in[0];
  const float* embed  = (const float*)d_in[1];
  const float* Wx     = (const float*)d_in[2];
  const float* Wh     = (const float*)d_in[3];
  const float* b_lstm = (const float*)d_in[4];
  const float* Wdp    = (const float*)d_in[5];
  const float* bdp    = (const float*)d_in[6];
  const float* Wenc   = (const float*)d_in[7];
  const float* benc   = (const float*)d_in[8];
  const float* Wout   = (const float*)d_in[9];
  const float* bout   = (const float*)d_in[10];
  float* out = (float*)d_out;
  char* ws = (char*)d_ws;
  unsigned long long* hw = (unsigned long long*)(ws + WS_HW);
  unsigned long long* xw = (unsigned long long*)(ws + WS_XW);
  unsigned long long* sA = (unsigned long long*)(ws + WS_SA);
  unsigned long long* sB = (unsigned long long*)(ws + WS_SB);
  unsigned* barflag = (unsigned*)(ws + WS_BAR);

  hipLaunchKernelGGL(rnnt_greedy3, dim3(NBLK), dim3(NTHR), 0, stream,
                     enc, embed, Wx, Wh, b_lstm, Wdp, bdp, Wenc, benc, Wout, bout,
                     out, hw, xw, sA, sB, barflag);
}